// Round 3
// baseline (724.977 us; speedup 1.0000x reference)
//
#include <hip/hip_runtime.h>

#define NN 100000
#define NE 1600000
#define D 128
#define ODIM 40

// ---------------- zero ----------------
__global__ void k_zero(int* __restrict__ p, int n) {
  int i = blockIdx.x * blockDim.x + threadIdx.x;
  if (i < n) p[i] = 0;
}

// ---------------- degree count ----------------
__global__ void k_count(const int* __restrict__ dst, int* __restrict__ counts) {
  int e = blockIdx.x * blockDim.x + threadIdx.x;
  if (e < NE) atomicAdd(&counts[dst[e]], 1);
}

// ---------------- scan: per-block partial sums + dinv ----------------
__global__ __launch_bounds__(256) void k_scan_partial(const int* __restrict__ counts,
    int* __restrict__ part, float* __restrict__ dinv) {
  __shared__ int red[256];
  int t = threadIdx.x;
  int base = blockIdx.x * 1024 + t * 4;
  int s = 0;
  for (int j = 0; j < 4; j++) {
    int idx = base + j;
    if (idx < NN) {
      int c = counts[idx];
      s += c;
      dinv[idx] = rsqrtf((float)(c + 1));
    }
  }
  red[t] = s;
  __syncthreads();
  for (int off = 128; off > 0; off >>= 1) {
    if (t < off) red[t] += red[t + off];
    __syncthreads();
  }
  if (t == 0) part[blockIdx.x] = red[0];
}

// ---------------- scan: serial carry over block partials ----------------
__global__ void k_scan_carry(int* __restrict__ part, int nb, int* __restrict__ offsets) {
  int acc = 0;
  for (int i = 0; i < nb; i++) {
    int v = part[i];
    part[i] = acc;
    acc += v;
  }
  offsets[NN] = acc;  // == NE
}

// ---------------- scan: final offsets ----------------
__global__ __launch_bounds__(256) void k_scan_final(const int* __restrict__ counts,
    const int* __restrict__ part, int* __restrict__ offsets) {
  __shared__ int lds[256];
  int t = threadIdx.x;
  int base = blockIdx.x * 1024 + t * 4;
  int v0 = 0, v1 = 0, v2 = 0, v3 = 0;
  if (base + 0 < NN) v0 = counts[base + 0];
  if (base + 1 < NN) v1 = counts[base + 1];
  if (base + 2 < NN) v2 = counts[base + 2];
  if (base + 3 < NN) v3 = counts[base + 3];
  int s = v0 + v1 + v2 + v3;
  lds[t] = s;
  __syncthreads();
  for (int off = 1; off < 256; off <<= 1) {
    int add = (t >= off) ? lds[t - off] : 0;
    __syncthreads();
    lds[t] += add;
    __syncthreads();
  }
  int run = lds[t] - s + part[blockIdx.x];  // exclusive prefix + block base
  if (base + 0 < NN) offsets[base + 0] = run;
  run += v0;
  if (base + 1 < NN) offsets[base + 1] = run;
  run += v1;
  if (base + 2 < NN) offsets[base + 2] = run;
  run += v2;
  if (base + 3 < NN) offsets[base + 3] = run;
}

// ---------------- CSR fill ----------------
__global__ void k_fill(const int* __restrict__ src, const int* __restrict__ dst,
    const int* __restrict__ offsets, int* __restrict__ fillc, int* __restrict__ csr) {
  int e = blockIdx.x * blockDim.x + threadIdx.x;
  if (e < NE) {
    int d = dst[e];
    int p = offsets[d] + atomicAdd(&fillc[d], 1);
    csr[p] = src[e];
  }
}

// ---------------- GEMM: H[N,128] = X[N,128] @ W[128,128] (no bias) ----------------
__global__ __launch_bounds__(256) void k_gemm128(const float* __restrict__ X,
    const float* __restrict__ W, float* __restrict__ H) {
  __shared__ __align__(16) float At[32][64];    // A chunk, transposed: At[k][n]
  __shared__ __align__(16) float Wl[32][128];   // W chunk: Wl[k][f]
  int tid = threadIdx.x;
  int ft = tid & 15;   // feature group: features ft*8 .. ft*8+7
  int nt = tid >> 4;   // node group: nodes nt*4 .. nt*4+3
  int nbase = blockIdx.x * 64;
  float acc[4][8];
#pragma unroll
  for (int i = 0; i < 4; i++)
#pragma unroll
    for (int j = 0; j < 8; j++) acc[i][j] = 0.f;

  for (int k0 = 0; k0 < D; k0 += 32) {
    {  // stage A transposed: 64 nodes x 32 k
      int n = tid >> 2;
      int kv = (tid & 3) * 8;
      int gn = nbase + n;
      if (gn >= NN) gn = NN - 1;
      const float4* xp = (const float4*)&X[gn * D + k0 + kv];
      float4 a0 = xp[0];
      float4 a1 = xp[1];
      At[kv + 0][n] = a0.x; At[kv + 1][n] = a0.y; At[kv + 2][n] = a0.z; At[kv + 3][n] = a0.w;
      At[kv + 4][n] = a1.x; At[kv + 5][n] = a1.y; At[kv + 6][n] = a1.z; At[kv + 7][n] = a1.w;
    }
    {  // stage W chunk: 32 x 128
      int r = tid >> 5;
      int c = (tid & 31) * 4;
#pragma unroll
      for (int rr = 0; rr < 32; rr += 8)
        *(float4*)&Wl[r + rr][c] = *(const float4*)&W[(k0 + r + rr) * D + c];
    }
    __syncthreads();
#pragma unroll 8
    for (int k = 0; k < 32; k++) {
      float4 a  = *(float4*)&At[k][nt * 4];
      float4 w0 = *(float4*)&Wl[k][ft * 8];
      float4 w1 = *(float4*)&Wl[k][ft * 8 + 4];
      float av[4] = {a.x, a.y, a.z, a.w};
      float wv[8] = {w0.x, w0.y, w0.z, w0.w, w1.x, w1.y, w1.z, w1.w};
#pragma unroll
      for (int i = 0; i < 4; i++)
#pragma unroll
        for (int j = 0; j < 8; j++)
          acc[i][j] = fmaf(av[i], wv[j], acc[i][j]);
    }
    __syncthreads();
  }
#pragma unroll
  for (int i = 0; i < 4; i++) {
    int gn = nbase + nt * 4 + i;
    if (gn < NN) {
      float4 o0 = {acc[i][0], acc[i][1], acc[i][2], acc[i][3]};
      float4 o1 = {acc[i][4], acc[i][5], acc[i][6], acc[i][7]};
      *(float4*)&H[gn * D + ft * 8]     = o0;
      *(float4*)&H[gn * D + ft * 8 + 4] = o1;
    }
  }
}

// ---------------- aggregate: out = relu(dinv[i]*Σ dinv[s]h[s] + dinv[i]^2 h[i] + b) ----------------
__global__ __launch_bounds__(256) void k_aggregate(const float* __restrict__ h,
    const int* __restrict__ csr, const int* __restrict__ offsets,
    const float* __restrict__ dinv, const float* __restrict__ bias,
    float* __restrict__ out) {
  int node = blockIdx.x * 4 + (threadIdx.x >> 6);
  int lane = threadIdx.x & 63;
  if (node >= NN) return;
  int beg = offsets[node];
  int end = offsets[node + 1];
  const float2* hv = (const float2*)h;
  float2 a0 = {0.f, 0.f}, a1 = {0.f, 0.f};
  int e = beg;
  for (; e + 1 < end; e += 2) {
    int s0 = csr[e];
    int s1 = csr[e + 1];
    float d0 = dinv[s0];
    float d1 = dinv[s1];
    float2 h0 = hv[s0 * 64 + lane];
    float2 h1 = hv[s1 * 64 + lane];
    a0.x = fmaf(h0.x, d0, a0.x); a0.y = fmaf(h0.y, d0, a0.y);
    a1.x = fmaf(h1.x, d1, a1.x); a1.y = fmaf(h1.y, d1, a1.y);
  }
  if (e < end) {
    int s0 = csr[e];
    float d0 = dinv[s0];
    float2 h0 = hv[s0 * 64 + lane];
    a0.x = fmaf(h0.x, d0, a0.x); a0.y = fmaf(h0.y, d0, a0.y);
  }
  float di = dinv[node];
  float2 hs = hv[node * 64 + lane];
  float2 b = *(const float2*)&bias[lane * 2];
  float o0 = fmaxf(di * (a0.x + a1.x) + di * di * hs.x + b.x, 0.f);
  float o1 = fmaxf(di * (a0.y + a1.y) + di * di * hs.y + b.y, 0.f);
  float2 o = {o0, o1};
  *(float2*)&out[node * D + lane * 2] = o;
}

// ---------------- classifier: out[N,40] = X[N,128] @ Wc[128,40] + bc ----------------
__global__ __launch_bounds__(256) void k_classifier(const float* __restrict__ X,
    const float* __restrict__ Wc, const float* __restrict__ bc, float* __restrict__ out) {
  __shared__ __align__(16) float wl[D * ODIM];   // 20 KB
  __shared__ __align__(16) float xl[50 * D];     // 25 KB
  int tid = threadIdx.x;
  for (int i = tid; i < D * ODIM; i += 256) wl[i] = Wc[i];
  int nbase = blockIdx.x * 50;
  for (int i = tid; i < 50 * D; i += 256) {
    int gn = nbase + (i >> 7);
    xl[i] = (gn < NN) ? X[gn * D + (i & 127)] : 0.f;
  }
  __syncthreads();
  int fg = tid % 10;   // feature group of 4
  int np = tid / 10;   // node pair
  if (np < 25) {
    float acc0[4] = {0, 0, 0, 0};
    float acc1[4] = {0, 0, 0, 0};
    const float* x0 = &xl[(np * 2) * D];
    const float* x1 = &xl[(np * 2 + 1) * D];
#pragma unroll 4
    for (int k = 0; k < D; k++) {
      float4 w = *(float4*)&wl[k * ODIM + fg * 4];
      float xv0 = x0[k];
      float xv1 = x1[k];
      acc0[0] = fmaf(xv0, w.x, acc0[0]); acc0[1] = fmaf(xv0, w.y, acc0[1]);
      acc0[2] = fmaf(xv0, w.z, acc0[2]); acc0[3] = fmaf(xv0, w.w, acc0[3]);
      acc1[0] = fmaf(xv1, w.x, acc1[0]); acc1[1] = fmaf(xv1, w.y, acc1[1]);
      acc1[2] = fmaf(xv1, w.z, acc1[2]); acc1[3] = fmaf(xv1, w.w, acc1[3]);
    }
    float4 b = *(const float4*)&bc[fg * 4];
    int gn0 = nbase + np * 2;
    int gn1 = gn0 + 1;
    if (gn0 < NN) {
      float4 o = {acc0[0] + b.x, acc0[1] + b.y, acc0[2] + b.z, acc0[3] + b.w};
      *(float4*)&out[gn0 * ODIM + fg * 4] = o;
    }
    if (gn1 < NN) {
      float4 o = {acc1[0] + b.x, acc1[1] + b.y, acc1[2] + b.z, acc1[3] + b.w};
      *(float4*)&out[gn1 * ODIM + fg * 4] = o;
    }
  }
}

extern "C" void kernel_launch(void* const* d_in, const int* in_sizes, int n_in,
                              void* d_out, int out_size, void* d_ws, size_t ws_size,
                              hipStream_t stream) {
  const float* fts = (const float*)d_in[0];
  const int*   ei  = (const int*)d_in[1];
  const float* W1  = (const float*)d_in[2];
  const float* b1  = (const float*)d_in[3];
  const float* W2  = (const float*)d_in[4];
  const float* b2  = (const float*)d_in[5];
  const float* Wc  = (const float*)d_in[6];
  const float* bc  = (const float*)d_in[7];
  const int* src = ei;        // edge_index[0]
  const int* dst = ei + NE;   // edge_index[1]

  // workspace layout (all 16B aligned)
  char* ws = (char*)d_ws;
  int*   counts  = (int*)(ws + 0);                 // 400000 B
  int*   fillc   = (int*)(ws + 400000);            // 400000 B
  int*   part    = (int*)(ws + 800000);            // 512 B
  int*   offsets = (int*)(ws + 800512);            // 400128 B (N+1 ints)
  float* dinv    = (float*)(ws + 1200640);         // 400000 B
  int*   csr     = (int*)(ws + 1600640);           // 6400000 B
  float* h       = (float*)(ws + 8000640);         // 51200000 B
  // total: ~59.2 MB of d_ws

  float* outc = (float*)d_out;              // [N,40]
  float* x    = (float*)d_out + NN * ODIM;  // [N,128]  (x1 lives here, overwritten by x2)

  int nb = (NN + 1023) / 1024;  // 98

  k_zero<<<(2 * NN + 255) / 256, 256, 0, stream>>>(counts, 2 * NN);
  k_count<<<(NE + 255) / 256, 256, 0, stream>>>(dst, counts);
  k_scan_partial<<<nb, 256, 0, stream>>>(counts, part, dinv);
  k_scan_carry<<<1, 1, 0, stream>>>(part, nb, offsets);
  k_scan_final<<<nb, 256, 0, stream>>>(counts, part, offsets);
  k_fill<<<(NE + 255) / 256, 256, 0, stream>>>(src, dst, offsets, fillc, csr);

  // layer 1: h = fts @ W1 ; x1 = relu(agg(h) + b1)
  k_gemm128<<<(NN + 63) / 64, 256, 0, stream>>>(fts, W1, h);
  k_aggregate<<<(NN + 3) / 4, 256, 0, stream>>>(h, csr, offsets, dinv, b1, x);
  // layer 2: h = x1 @ W2 ; x2 = relu(agg(h) + b2)
  k_gemm128<<<(NN + 63) / 64, 256, 0, stream>>>(x, W2, h);
  k_aggregate<<<(NN + 3) / 4, 256, 0, stream>>>(h, csr, offsets, dinv, b2, x);
  // classifier
  k_classifier<<<(NN + 49) / 50, 256, 0, stream>>>(x, Wc, bc, outc);
}

// Round 5
// 571.339 us; speedup vs baseline: 1.2689x; 1.2689x over previous
//
#include <hip/hip_runtime.h>

#define NN 100000
#define NE 1600000
#define D 128
#define ODIM 40

typedef unsigned int uint;
typedef unsigned short ushort;

// bf16 helpers: h is stored as bf16 (packed pairs in uint); math is fp32.
__device__ __forceinline__ uint pack_bf16x2(float lo, float hi) {
  uint ul = __float_as_uint(lo);
  uint uh = __float_as_uint(hi);
  ul = (ul + 0x7FFFu + ((ul >> 16) & 1u)) >> 16;   // RNE
  uh = (uh + 0x7FFFu + ((uh >> 16) & 1u)) >> 16;
  return ul | (uh << 16);
}
__device__ __forceinline__ float bf_lo(uint u) { return __uint_as_float(u << 16); }
__device__ __forceinline__ float bf_hi(uint u) { return __uint_as_float(u & 0xFFFF0000u); }

// ---------------- zero ----------------
__global__ void k_zero(int* __restrict__ p, int n) {
  int i = blockIdx.x * blockDim.x + threadIdx.x;
  if (i < n) p[i] = 0;
}

// ---------------- degree count ----------------
__global__ void k_count(const int* __restrict__ dst, int* __restrict__ counts) {
  int e = blockIdx.x * blockDim.x + threadIdx.x;
  if (e < NE) atomicAdd(&counts[dst[e]], 1);
}

// ---------------- scan: per-block partial sums + dinv ----------------
__global__ __launch_bounds__(256) void k_scan_partial(const int* __restrict__ counts,
    int* __restrict__ part, float* __restrict__ dinv) {
  __shared__ int red[256];
  int t = threadIdx.x;
  int base = blockIdx.x * 1024 + t * 4;
  int s = 0;
  for (int j = 0; j < 4; j++) {
    int idx = base + j;
    if (idx < NN) {
      int c = counts[idx];
      s += c;
      dinv[idx] = rsqrtf((float)(c + 1));
    }
  }
  red[t] = s;
  __syncthreads();
  for (int off = 128; off > 0; off >>= 1) {
    if (t < off) red[t] += red[t + off];
    __syncthreads();
  }
  if (t == 0) part[blockIdx.x] = red[0];
}

// ---------------- scan: parallel carry over block partials (nb <= 128) ----------------
__global__ __launch_bounds__(128) void k_scan_carry(int* __restrict__ part, int nb,
                                                    int* __restrict__ offsets) {
  __shared__ int l[128];
  int t = threadIdx.x;
  int v = (t < nb) ? part[t] : 0;
  l[t] = v;
  __syncthreads();
  for (int off = 1; off < 128; off <<= 1) {
    int add = (t >= off) ? l[t - off] : 0;
    __syncthreads();
    l[t] += add;
    __syncthreads();
  }
  if (t < nb) part[t] = l[t] - v;        // exclusive prefix
  if (t == 127) offsets[NN] = l[127];    // total == NE
}

// ---------------- scan: final offsets ----------------
__global__ __launch_bounds__(256) void k_scan_final(const int* __restrict__ counts,
    const int* __restrict__ part, int* __restrict__ offsets) {
  __shared__ int lds[256];
  int t = threadIdx.x;
  int base = blockIdx.x * 1024 + t * 4;
  int v0 = 0, v1 = 0, v2 = 0, v3 = 0;
  if (base + 0 < NN) v0 = counts[base + 0];
  if (base + 1 < NN) v1 = counts[base + 1];
  if (base + 2 < NN) v2 = counts[base + 2];
  if (base + 3 < NN) v3 = counts[base + 3];
  int s = v0 + v1 + v2 + v3;
  lds[t] = s;
  __syncthreads();
  for (int off = 1; off < 256; off <<= 1) {
    int add = (t >= off) ? lds[t - off] : 0;
    __syncthreads();
    lds[t] += add;
    __syncthreads();
  }
  int run = lds[t] - s + part[blockIdx.x];  // exclusive prefix + block base
  if (base + 0 < NN) offsets[base + 0] = run;
  run += v0;
  if (base + 1 < NN) offsets[base + 1] = run;
  run += v1;
  if (base + 2 < NN) offsets[base + 2] = run;
  run += v2;
  if (base + 3 < NN) offsets[base + 3] = run;
}

// ---------------- CSR fill ----------------
__global__ void k_fill(const int* __restrict__ src, const int* __restrict__ dst,
    const int* __restrict__ offsets, int* __restrict__ fillc, int* __restrict__ csr) {
  int e = blockIdx.x * blockDim.x + threadIdx.x;
  if (e < NE) {
    int d = dst[e];
    int p = offsets[d] + atomicAdd(&fillc[d], 1);
    csr[p] = src[e];
  }
}

// ---------------- GEMM: H[N,128] = bf16(X[N,128] @ W[128,128]) ----------------
__global__ __launch_bounds__(256) void k_gemm128(const float* __restrict__ X,
    const float* __restrict__ W, ushort* __restrict__ H) {
  __shared__ __align__(16) float At[32][64];    // A chunk, transposed: At[k][n]
  __shared__ __align__(16) float Wl[32][128];   // W chunk: Wl[k][f]
  int tid = threadIdx.x;
  int ft = tid & 15;   // feature group: features ft*8 .. ft*8+7
  int nt = tid >> 4;   // node group: nodes nt*4 .. nt*4+3
  int nbase = blockIdx.x * 64;
  float acc[4][8];
#pragma unroll
  for (int i = 0; i < 4; i++)
#pragma unroll
    for (int j = 0; j < 8; j++) acc[i][j] = 0.f;

  for (int k0 = 0; k0 < D; k0 += 32) {
    {  // stage A transposed: 64 nodes x 32 k
      int n = tid >> 2;
      int kv = (tid & 3) * 8;
      int gn = nbase + n;
      if (gn >= NN) gn = NN - 1;
      const float4* xp = (const float4*)&X[gn * D + k0 + kv];
      float4 a0 = xp[0];
      float4 a1 = xp[1];
      At[kv + 0][n] = a0.x; At[kv + 1][n] = a0.y; At[kv + 2][n] = a0.z; At[kv + 3][n] = a0.w;
      At[kv + 4][n] = a1.x; At[kv + 5][n] = a1.y; At[kv + 6][n] = a1.z; At[kv + 7][n] = a1.w;
    }
    {  // stage W chunk: 32 x 128
      int r = tid >> 5;
      int c = (tid & 31) * 4;
#pragma unroll
      for (int rr = 0; rr < 32; rr += 8)
        *(float4*)&Wl[r + rr][c] = *(const float4*)&W[(k0 + r + rr) * D + c];
    }
    __syncthreads();
#pragma unroll 8
    for (int k = 0; k < 32; k++) {
      float4 a  = *(float4*)&At[k][nt * 4];
      float4 w0 = *(float4*)&Wl[k][ft * 8];
      float4 w1 = *(float4*)&Wl[k][ft * 8 + 4];
      float av[4] = {a.x, a.y, a.z, a.w};
      float wv[8] = {w0.x, w0.y, w0.z, w0.w, w1.x, w1.y, w1.z, w1.w};
#pragma unroll
      for (int i = 0; i < 4; i++)
#pragma unroll
        for (int j = 0; j < 8; j++)
          acc[i][j] = fmaf(av[i], wv[j], acc[i][j]);
    }
    __syncthreads();
  }
#pragma unroll
  for (int i = 0; i < 4; i++) {
    int gn = nbase + nt * 4 + i;
    if (gn < NN) {
      uint4 o;
      o.x = pack_bf16x2(acc[i][0], acc[i][1]);
      o.y = pack_bf16x2(acc[i][2], acc[i][3]);
      o.z = pack_bf16x2(acc[i][4], acc[i][5]);
      o.w = pack_bf16x2(acc[i][6], acc[i][7]);
      *(uint4*)&H[gn * D + ft * 8] = o;   // (gn*128+ft*8)*2 bytes, 16B aligned
    }
  }
}

// ---- aggregate: x = relu(dinv[i]*Σ dinv[s]h[s] + dinv[i]^2 h[i] + b), h in bf16 ----
__global__ __launch_bounds__(256) void k_aggregate(const ushort* __restrict__ h,
    const int* __restrict__ csr, const int* __restrict__ offsets,
    const float* __restrict__ dinv, const float* __restrict__ bias,
    float* __restrict__ out) {
  int node = blockIdx.x * 4 + (threadIdx.x >> 6);
  int lane = threadIdx.x & 63;
  if (node >= NN) return;
  int beg = offsets[node];
  int end = offsets[node + 1];
  const uint* hv = (const uint*)h;   // one uint = 2 bf16 features; row = 64 uints
  float a0x = 0.f, a0y = 0.f, a1x = 0.f, a1y = 0.f;
  float a2x = 0.f, a2y = 0.f, a3x = 0.f, a3y = 0.f;
  int e = beg;
  for (; e + 3 < end; e += 4) {
    int s0 = csr[e], s1 = csr[e + 1], s2 = csr[e + 2], s3 = csr[e + 3];
    float d0 = dinv[s0], d1 = dinv[s1], d2 = dinv[s2], d3 = dinv[s3];
    uint u0 = hv[s0 * 64 + lane];
    uint u1 = hv[s1 * 64 + lane];
    uint u2 = hv[s2 * 64 + lane];
    uint u3 = hv[s3 * 64 + lane];
    a0x = fmaf(bf_lo(u0), d0, a0x); a0y = fmaf(bf_hi(u0), d0, a0y);
    a1x = fmaf(bf_lo(u1), d1, a1x); a1y = fmaf(bf_hi(u1), d1, a1y);
    a2x = fmaf(bf_lo(u2), d2, a2x); a2y = fmaf(bf_hi(u2), d2, a2y);
    a3x = fmaf(bf_lo(u3), d3, a3x); a3y = fmaf(bf_hi(u3), d3, a3y);
  }
  for (; e < end; e++) {
    int s0 = csr[e];
    float d0 = dinv[s0];
    uint u0 = hv[s0 * 64 + lane];
    a0x = fmaf(bf_lo(u0), d0, a0x); a0y = fmaf(bf_hi(u0), d0, a0y);
  }
  float di = dinv[node];
  uint us = hv[node * 64 + lane];
  float2 b = *(const float2*)&bias[lane * 2];
  float sx = (a0x + a1x) + (a2x + a3x);
  float sy = (a0y + a1y) + (a2y + a3y);
  float o0 = fmaxf(fmaf(di, sx, fmaf(di * di, bf_lo(us), b.x)), 0.f);
  float o1 = fmaxf(fmaf(di, sy, fmaf(di * di, bf_hi(us), b.y)), 0.f);
  float2 o = {o0, o1};
  *(float2*)&out[node * D + lane * 2] = o;
}

// ---------------- classifier: out[N,40] = X[N,128] @ Wc[128,40] + bc ----------------
__global__ __launch_bounds__(256) void k_classifier(const float* __restrict__ X,
    const float* __restrict__ Wc, const float* __restrict__ bc, float* __restrict__ out) {
  __shared__ __align__(16) float wl[D * ODIM];   // 20 KB
  __shared__ __align__(16) float xl[50 * D];     // 25 KB
  int tid = threadIdx.x;
  for (int i = tid; i < D * ODIM; i += 256) wl[i] = Wc[i];
  int nbase = blockIdx.x * 50;
  for (int i = tid; i < 50 * D; i += 256) {
    int gn = nbase + (i >> 7);
    xl[i] = (gn < NN) ? X[gn * D + (i & 127)] : 0.f;
  }
  __syncthreads();
  int fg = tid % 10;   // feature group of 4
  int np = tid / 10;   // node pair
  if (np < 25) {
    float acc0[4] = {0, 0, 0, 0};
    float acc1[4] = {0, 0, 0, 0};
    const float* x0 = &xl[(np * 2) * D];
    const float* x1 = &xl[(np * 2 + 1) * D];
#pragma unroll 4
    for (int k = 0; k < D; k++) {
      float4 w = *(float4*)&wl[k * ODIM + fg * 4];
      float xv0 = x0[k];
      float xv1 = x1[k];
      acc0[0] = fmaf(xv0, w.x, acc0[0]); acc0[1] = fmaf(xv0, w.y, acc0[1]);
      acc0[2] = fmaf(xv0, w.z, acc0[2]); acc0[3] = fmaf(xv0, w.w, acc0[3]);
      acc1[0] = fmaf(xv1, w.x, acc1[0]); acc1[1] = fmaf(xv1, w.y, acc1[1]);
      acc1[2] = fmaf(xv1, w.z, acc1[2]); acc1[3] = fmaf(xv1, w.w, acc1[3]);
    }
    float4 b = *(const float4*)&bc[fg * 4];
    int gn0 = nbase + np * 2;
    int gn1 = gn0 + 1;
    if (gn0 < NN) {
      float4 o = {acc0[0] + b.x, acc0[1] + b.y, acc0[2] + b.z, acc0[3] + b.w};
      *(float4*)&out[gn0 * ODIM + fg * 4] = o;
    }
    if (gn1 < NN) {
      float4 o = {acc1[0] + b.x, acc1[1] + b.y, acc1[2] + b.z, acc1[3] + b.w};
      *(float4*)&out[gn1 * ODIM + fg * 4] = o;
    }
  }
}

extern "C" void kernel_launch(void* const* d_in, const int* in_sizes, int n_in,
                              void* d_out, int out_size, void* d_ws, size_t ws_size,
                              hipStream_t stream) {
  const float* fts = (const float*)d_in[0];
  const int*   ei  = (const int*)d_in[1];
  const float* W1  = (const float*)d_in[2];
  const float* b1  = (const float*)d_in[3];
  const float* W2  = (const float*)d_in[4];
  const float* b2  = (const float*)d_in[5];
  const float* Wc  = (const float*)d_in[6];
  const float* bc  = (const float*)d_in[7];
  const int* src = ei;        // edge_index[0]
  const int* dst = ei + NE;   // edge_index[1]

  // workspace layout (all 16B aligned)
  char* ws = (char*)d_ws;
  int*    counts  = (int*)(ws + 0);                 // 400000 B
  int*    fillc   = (int*)(ws + 400000);            // 400000 B
  int*    part    = (int*)(ws + 800000);            // 512 B
  int*    offsets = (int*)(ws + 800512);            // 400128 B (N+1 ints)
  float*  dinv    = (float*)(ws + 1200640);         // 400000 B
  int*    csr     = (int*)(ws + 1600640);           // 6400000 B
  ushort* h       = (ushort*)(ws + 8000640);        // 25600000 B (bf16)
  // total: ~33.6 MB of d_ws

  float* outc = (float*)d_out;              // [N,40]
  float* x    = (float*)d_out + NN * ODIM;  // [N,128]  (x1 lives here, overwritten by x2)

  int nb = (NN + 1023) / 1024;  // 98

  k_zero<<<(2 * NN + 255) / 256, 256, 0, stream>>>(counts, 2 * NN);
  k_count<<<(NE + 255) / 256, 256, 0, stream>>>(dst, counts);
  k_scan_partial<<<nb, 256, 0, stream>>>(counts, part, dinv);
  k_scan_carry<<<1, 128, 0, stream>>>(part, nb, offsets);
  k_scan_final<<<nb, 256, 0, stream>>>(counts, part, offsets);
  k_fill<<<(NE + 255) / 256, 256, 0, stream>>>(src, dst, offsets, fillc, csr);

  // layer 1: h = bf16(fts @ W1) ; x1 = relu(agg(h) + b1)
  k_gemm128<<<(NN + 63) / 64, 256, 0, stream>>>(fts, W1, h);
  k_aggregate<<<(NN + 3) / 4, 256, 0, stream>>>(h, csr, offsets, dinv, b1, x);
  // layer 2: h = bf16(x1 @ W2) ; x2 = relu(agg(h) + b2)
  k_gemm128<<<(NN + 63) / 64, 256, 0, stream>>>(x, W2, h);
  k_aggregate<<<(NN + 3) / 4, 256, 0, stream>>>(h, csr, offsets, dinv, b2, x);
  // classifier
  k_classifier<<<(NN + 49) / 50, 256, 0, stream>>>(x, Wc, bc, outc);
}

// Round 6
// 541.409 us; speedup vs baseline: 1.3391x; 1.0553x over previous
//
#include <hip/hip_runtime.h>

#define NN 100000
#define NE 1600000
#define D 128
#define ODIM 40
#define CHUNK 16384
#define NBUCK 196      // ceil(NN/512)
#define BCAP 10240     // bucket capacity in LDS (mean 8192, sigma~90 -> +22 sigma)

typedef unsigned int uint;
typedef unsigned short ushort;

// bf16 helpers: h is stored as bf16 (packed pairs in uint); math is fp32.
__device__ __forceinline__ uint pack_bf16x2(float lo, float hi) {
  uint ul = __float_as_uint(lo);
  uint uh = __float_as_uint(hi);
  ul = (ul + 0x7FFFu + ((ul >> 16) & 1u)) >> 16;   // RNE
  uh = (uh + 0x7FFFu + ((uh >> 16) & 1u)) >> 16;
  return ul | (uh << 16);
}
__device__ __forceinline__ float bf_lo(uint u) { return __uint_as_float(u << 16); }
__device__ __forceinline__ float bf_hi(uint u) { return __uint_as_float(u & 0xFFFF0000u); }

// ---------------- zero ----------------
__global__ void k_zero(int* __restrict__ p, int n) {
  int i = blockIdx.x * blockDim.x + threadIdx.x;
  if (i < n) p[i] = 0;
}

// ---------------- degree count ----------------
__global__ void k_count(const int* __restrict__ dst, int* __restrict__ counts) {
  int e = blockIdx.x * blockDim.x + threadIdx.x;
  if (e < NE) atomicAdd(&counts[dst[e]], 1);
}

// ---------------- scan: per-block partial sums + dinv ----------------
__global__ __launch_bounds__(256) void k_scan_partial(const int* __restrict__ counts,
    int* __restrict__ part, float* __restrict__ dinv) {
  __shared__ int red[256];
  int t = threadIdx.x;
  int base = blockIdx.x * 1024 + t * 4;
  int s = 0;
  for (int j = 0; j < 4; j++) {
    int idx = base + j;
    if (idx < NN) {
      int c = counts[idx];
      s += c;
      dinv[idx] = rsqrtf((float)(c + 1));
    }
  }
  red[t] = s;
  __syncthreads();
  for (int off = 128; off > 0; off >>= 1) {
    if (t < off) red[t] += red[t + off];
    __syncthreads();
  }
  if (t == 0) part[blockIdx.x] = red[0];
}

// ---------------- scan: parallel carry over block partials (nb <= 128) ----------------
__global__ __launch_bounds__(128) void k_scan_carry(int* __restrict__ part, int nb,
                                                    int* __restrict__ offsets) {
  __shared__ int l[128];
  int t = threadIdx.x;
  int v = (t < nb) ? part[t] : 0;
  l[t] = v;
  __syncthreads();
  for (int off = 1; off < 128; off <<= 1) {
    int add = (t >= off) ? l[t - off] : 0;
    __syncthreads();
    l[t] += add;
    __syncthreads();
  }
  if (t < nb) part[t] = l[t] - v;        // exclusive prefix
  if (t == 127) offsets[NN] = l[127];    // total == NE
}

// ---------------- scan: final offsets ----------------
__global__ __launch_bounds__(256) void k_scan_final(const int* __restrict__ counts,
    const int* __restrict__ part, int* __restrict__ offsets) {
  __shared__ int lds[256];
  int t = threadIdx.x;
  int base = blockIdx.x * 1024 + t * 4;
  int v0 = 0, v1 = 0, v2 = 0, v3 = 0;
  if (base + 0 < NN) v0 = counts[base + 0];
  if (base + 1 < NN) v1 = counts[base + 1];
  if (base + 2 < NN) v2 = counts[base + 2];
  if (base + 3 < NN) v3 = counts[base + 3];
  int s = v0 + v1 + v2 + v3;
  lds[t] = s;
  __syncthreads();
  for (int off = 1; off < 256; off <<= 1) {
    int add = (t >= off) ? lds[t - off] : 0;
    __syncthreads();
    lds[t] += add;
    __syncthreads();
  }
  int run = lds[t] - s + part[blockIdx.x];  // exclusive prefix + block base
  if (base + 0 < NN) offsets[base + 0] = run;
  run += v0;
  if (base + 1 < NN) offsets[base + 1] = run;
  run += v1;
  if (base + 2 < NN) offsets[base + 2] = run;
  run += v2;
  if (base + 3 < NN) offsets[base + 3] = run;
}

// ---- pass A: bin edges into 196 dst-buckets (512 nodes each), pairs (src,dst) ----
// Per-bucket runs are written sequentially by one block (=one XCD L2) -> lines
// fill completely before writeback; kills k_fill's 107MB write amplification.
__global__ __launch_bounds__(256) void k_bin(const int* __restrict__ src,
    const int* __restrict__ dst, const int* __restrict__ offsets,
    int* __restrict__ bucketFill, uint2* __restrict__ ebuf) {
  __shared__ int hist[NBUCK];
  __shared__ int hist2[NBUCK];
  __shared__ int gb[NBUCK];
  int tid = threadIdx.x;
  int base = blockIdx.x * CHUNK;
  int n = NE - base;
  if (n > CHUNK) n = CHUNK;
  for (int i = tid; i < NBUCK; i += 256) { hist[i] = 0; hist2[i] = 0; }
  __syncthreads();
  for (int i = tid; i < n; i += 256) {
    int d = dst[base + i];
    atomicAdd(&hist[d >> 9], 1);
  }
  __syncthreads();
  for (int i = tid; i < NBUCK; i += 256) {
    int cnt = hist[i];
    int off = (cnt > 0) ? atomicAdd(&bucketFill[i], cnt) : 0;
    gb[i] = offsets[i << 9] + off;   // bucket region base + this chunk's slice
  }
  __syncthreads();
  for (int i = tid; i < n; i += 256) {
    int s = src[base + i];
    int d = dst[base + i];
    int b = d >> 9;
    int lp = atomicAdd(&hist2[b], 1);
    ebuf[gb[b] + lp] = make_uint2((uint)s, (uint)d);
  }
}

// ---- pass B: per-bucket CSR fill entirely in LDS, then coalesced write-out ----
__global__ __launch_bounds__(256) void k_fillb(const uint2* __restrict__ ebuf,
    const int* __restrict__ offsets, int* __restrict__ fillc, int* __restrict__ csr) {
  __shared__ int loff[513];
  __shared__ int lfill[512];
  __shared__ int limage[BCAP];
  int tid = threadIdx.x;
  int nb0 = blockIdx.x << 9;
  int nb1 = nb0 + 512; if (nb1 > NN) nb1 = NN;
  int nnodes = nb1 - nb0;
  int bbase = offsets[nb0];
  for (int i = tid; i <= nnodes; i += 256) loff[i] = offsets[nb0 + i] - bbase;
  for (int i = tid; i < nnodes; i += 256) lfill[i] = 0;
  __syncthreads();
  int bn = loff[nnodes];
  if (bn <= BCAP) {
    for (int i = tid; i < bn; i += 256) {
      uint2 p = ebuf[bbase + i];
      int dl = (int)p.y - nb0;
      int lp = atomicAdd(&lfill[dl], 1);
      limage[loff[dl] + lp] = (int)p.x;
    }
    __syncthreads();
    for (int i = tid; i < bn; i += 256) csr[bbase + i] = limage[i];
  } else {
    // statistically unreachable overflow fallback (correct, slow)
    for (int i = tid; i < bn; i += 256) {
      uint2 p = ebuf[bbase + i];
      int dnode = (int)p.y;
      int lp = atomicAdd(&fillc[dnode], 1);
      csr[offsets[dnode] + lp] = (int)p.x;
    }
  }
}

// ---- GEMM: H[N,128] = bf16( dinv[n] * (X[N,128] @ W[128,128]) ) ----
__global__ __launch_bounds__(256) void k_gemm128(const float* __restrict__ X,
    const float* __restrict__ W, const float* __restrict__ dinv, ushort* __restrict__ H) {
  __shared__ __align__(16) float At[32][64];    // A chunk, transposed: At[k][n]
  __shared__ __align__(16) float Wl[32][128];   // W chunk: Wl[k][f]
  int tid = threadIdx.x;
  int ft = tid & 15;   // feature group: features ft*8 .. ft*8+7
  int nt = tid >> 4;   // node group: nodes nt*4 .. nt*4+3
  int nbase = blockIdx.x * 64;
  float acc[4][8];
#pragma unroll
  for (int i = 0; i < 4; i++)
#pragma unroll
    for (int j = 0; j < 8; j++) acc[i][j] = 0.f;

  for (int k0 = 0; k0 < D; k0 += 32) {
    {  // stage A transposed: 64 nodes x 32 k
      int n = tid >> 2;
      int kv = (tid & 3) * 8;
      int gn = nbase + n;
      if (gn >= NN) gn = NN - 1;
      const float4* xp = (const float4*)&X[gn * D + k0 + kv];
      float4 a0 = xp[0];
      float4 a1 = xp[1];
      At[kv + 0][n] = a0.x; At[kv + 1][n] = a0.y; At[kv + 2][n] = a0.z; At[kv + 3][n] = a0.w;
      At[kv + 4][n] = a1.x; At[kv + 5][n] = a1.y; At[kv + 6][n] = a1.z; At[kv + 7][n] = a1.w;
    }
    {  // stage W chunk: 32 x 128
      int r = tid >> 5;
      int c = (tid & 31) * 4;
#pragma unroll
      for (int rr = 0; rr < 32; rr += 8)
        *(float4*)&Wl[r + rr][c] = *(const float4*)&W[(k0 + r + rr) * D + c];
    }
    __syncthreads();
#pragma unroll 8
    for (int k = 0; k < 32; k++) {
      float4 a  = *(float4*)&At[k][nt * 4];
      float4 w0 = *(float4*)&Wl[k][ft * 8];
      float4 w1 = *(float4*)&Wl[k][ft * 8 + 4];
      float av[4] = {a.x, a.y, a.z, a.w};
      float wv[8] = {w0.x, w0.y, w0.z, w0.w, w1.x, w1.y, w1.z, w1.w};
#pragma unroll
      for (int i = 0; i < 4; i++)
#pragma unroll
        for (int j = 0; j < 8; j++)
          acc[i][j] = fmaf(av[i], wv[j], acc[i][j]);
    }
    __syncthreads();
  }
#pragma unroll
  for (int i = 0; i < 4; i++) {
    int gn = nbase + nt * 4 + i;
    if (gn < NN) {
      float di = dinv[gn];
      uint4 o;
      o.x = pack_bf16x2(acc[i][0] * di, acc[i][1] * di);
      o.y = pack_bf16x2(acc[i][2] * di, acc[i][3] * di);
      o.z = pack_bf16x2(acc[i][4] * di, acc[i][5] * di);
      o.w = pack_bf16x2(acc[i][6] * di, acc[i][7] * di);
      *(uint4*)&H[gn * D + ft * 8] = o;   // 16B aligned
    }
  }
}

// ---- aggregate: x = relu( dinv[i] * (Sum h'[s] + h'[i]) + b ), h' = dinv*h in bf16 ----
__global__ __launch_bounds__(256) void k_aggregate(const ushort* __restrict__ h,
    const int* __restrict__ csr, const int* __restrict__ offsets,
    const float* __restrict__ dinv, const float* __restrict__ bias,
    float* __restrict__ out) {
  int node = blockIdx.x * 4 + (threadIdx.x >> 6);
  int lane = threadIdx.x & 63;
  if (node >= NN) return;
  int beg = offsets[node];
  int end = offsets[node + 1];
  const uint* hv = (const uint*)h;   // one uint = 2 bf16 features; row = 64 uints
  float a0x = 0.f, a0y = 0.f, a1x = 0.f, a1y = 0.f;
  float a2x = 0.f, a2y = 0.f, a3x = 0.f, a3y = 0.f;
  int e = beg;
  for (; e + 3 < end; e += 4) {
    int s0 = csr[e], s1 = csr[e + 1], s2 = csr[e + 2], s3 = csr[e + 3];
    uint u0 = hv[s0 * 64 + lane];
    uint u1 = hv[s1 * 64 + lane];
    uint u2 = hv[s2 * 64 + lane];
    uint u3 = hv[s3 * 64 + lane];
    a0x += bf_lo(u0); a0y += bf_hi(u0);
    a1x += bf_lo(u1); a1y += bf_hi(u1);
    a2x += bf_lo(u2); a2y += bf_hi(u2);
    a3x += bf_lo(u3); a3y += bf_hi(u3);
  }
  for (; e < end; e++) {
    int s0 = csr[e];
    uint u0 = hv[s0 * 64 + lane];
    a0x += bf_lo(u0); a0y += bf_hi(u0);
  }
  float di = dinv[node];
  uint us = hv[node * 64 + lane];
  float2 b = *(const float2*)&bias[lane * 2];
  float sx = (a0x + a1x) + (a2x + a3x) + bf_lo(us);
  float sy = (a0y + a1y) + (a2y + a3y) + bf_hi(us);
  float o0 = fmaxf(fmaf(di, sx, b.x), 0.f);
  float o1 = fmaxf(fmaf(di, sy, b.y), 0.f);
  float2 o = {o0, o1};
  *(float2*)&out[node * D + lane * 2] = o;
}

// ---------------- classifier: out[N,40] = X[N,128] @ Wc[128,40] + bc ----------------
__global__ __launch_bounds__(256) void k_classifier(const float* __restrict__ X,
    const float* __restrict__ Wc, const float* __restrict__ bc, float* __restrict__ out) {
  __shared__ __align__(16) float wl[D * ODIM];   // 20 KB
  __shared__ __align__(16) float xl[50 * D];     // 25 KB
  int tid = threadIdx.x;
  for (int i = tid; i < D * ODIM; i += 256) wl[i] = Wc[i];
  int nbase = blockIdx.x * 50;
  for (int i = tid; i < 50 * D; i += 256) {
    int gn = nbase + (i >> 7);
    xl[i] = (gn < NN) ? X[gn * D + (i & 127)] : 0.f;
  }
  __syncthreads();
  int fg = tid % 10;   // feature group of 4
  int np = tid / 10;   // node pair
  if (np < 25) {
    float acc0[4] = {0, 0, 0, 0};
    float acc1[4] = {0, 0, 0, 0};
    const float* x0 = &xl[(np * 2) * D];
    const float* x1 = &xl[(np * 2 + 1) * D];
#pragma unroll 4
    for (int k = 0; k < D; k++) {
      float4 w = *(float4*)&wl[k * ODIM + fg * 4];
      float xv0 = x0[k];
      float xv1 = x1[k];
      acc0[0] = fmaf(xv0, w.x, acc0[0]); acc0[1] = fmaf(xv0, w.y, acc0[1]);
      acc0[2] = fmaf(xv0, w.z, acc0[2]); acc0[3] = fmaf(xv0, w.w, acc0[3]);
      acc1[0] = fmaf(xv1, w.x, acc1[0]); acc1[1] = fmaf(xv1, w.y, acc1[1]);
      acc1[2] = fmaf(xv1, w.z, acc1[2]); acc1[3] = fmaf(xv1, w.w, acc1[3]);
    }
    float4 b = *(const float4*)&bc[fg * 4];
    int gn0 = nbase + np * 2;
    int gn1 = gn0 + 1;
    if (gn0 < NN) {
      float4 o = {acc0[0] + b.x, acc0[1] + b.y, acc0[2] + b.z, acc0[3] + b.w};
      *(float4*)&out[gn0 * ODIM + fg * 4] = o;
    }
    if (gn1 < NN) {
      float4 o = {acc1[0] + b.x, acc1[1] + b.y, acc1[2] + b.z, acc1[3] + b.w};
      *(float4*)&out[gn1 * ODIM + fg * 4] = o;
    }
  }
}

extern "C" void kernel_launch(void* const* d_in, const int* in_sizes, int n_in,
                              void* d_out, int out_size, void* d_ws, size_t ws_size,
                              hipStream_t stream) {
  const float* fts = (const float*)d_in[0];
  const int*   ei  = (const int*)d_in[1];
  const float* W1  = (const float*)d_in[2];
  const float* b1  = (const float*)d_in[3];
  const float* W2  = (const float*)d_in[4];
  const float* b2  = (const float*)d_in[5];
  const float* Wc  = (const float*)d_in[6];
  const float* bc  = (const float*)d_in[7];
  const int* src = ei;        // edge_index[0]
  const int* dst = ei + NE;   // edge_index[1]

  // workspace layout (16B-aligned offsets)
  char* ws = (char*)d_ws;
  int*    counts     = (int*)(ws + 0);              // 400000 B
  int*    fillc      = (int*)(ws + 400000);         // 400000 B (overflow fallback only)
  int*    bucketFill = (int*)(ws + 800000);         // 1024 B
  int*    part       = (int*)(ws + 801024);         // 512 B
  int*    offsets    = (int*)(ws + 801536);         // 400128 B (N+1 ints)
  float*  dinv       = (float*)(ws + 1201664);      // 400000 B
  int*    csr        = (int*)(ws + 1601664);        // 6400000 B
  uint2*  ebuf       = (uint2*)(ws + 8001664);      // 12800000 B
  ushort* h          = (ushort*)(ws + 20801664);    // 25600000 B (bf16)
  // total ~46.4 MB

  float* outc = (float*)d_out;              // [N,40]
  float* x    = (float*)d_out + NN * ODIM;  // [N,128]  (x1 lives here, overwritten by x2)

  int nb = (NN + 1023) / 1024;  // 98

  k_zero<<<(2 * NN + 256 + 255) / 256, 256, 0, stream>>>(counts, 2 * NN + 256);
  k_count<<<(NE + 255) / 256, 256, 0, stream>>>(dst, counts);
  k_scan_partial<<<nb, 256, 0, stream>>>(counts, part, dinv);
  k_scan_carry<<<1, 128, 0, stream>>>(part, nb, offsets);
  k_scan_final<<<nb, 256, 0, stream>>>(counts, part, offsets);
  k_bin<<<(NE + CHUNK - 1) / CHUNK, 256, 0, stream>>>(src, dst, offsets, bucketFill, ebuf);
  k_fillb<<<NBUCK, 256, 0, stream>>>(ebuf, offsets, fillc, csr);

  // layer 1: h = bf16(dinv * (fts @ W1)) ; x1 = relu(dinv*(sum+self) + b1)
  k_gemm128<<<(NN + 63) / 64, 256, 0, stream>>>(fts, W1, dinv, h);
  k_aggregate<<<(NN + 3) / 4, 256, 0, stream>>>(h, csr, offsets, dinv, b1, x);
  // layer 2
  k_gemm128<<<(NN + 63) / 64, 256, 0, stream>>>(x, W2, dinv, h);
  k_aggregate<<<(NN + 3) / 4, 256, 0, stream>>>(h, csr, offsets, dinv, b2, x);
  // classifier
  k_classifier<<<(NN + 49) / 50, 256, 0, stream>>>(x, Wc, bc, outc);
}